// Round 2
// baseline (752.569 us; speedup 1.0000x reference)
//
#include <hip/hip_runtime.h>
#include <stdint.h>

// Problem constants (QSGDLinear): out = x @ W^T
//   x: (2,1024,4096) fp32 -> M=2048, K=4096
//   ternary: (16384,4096) int32 in {-1,0,1} -> N=16384
//   scales: (16384*4096/128,) fp32, group = contiguous 128 along K of one row
#define M_ROWS 2048
#define IN_F   4096
#define OUT_F  16384

#define BM 256
#define BN 256
#define BK 32
#define NT (IN_F / BK)   // 128 k-tiles

typedef __attribute__((ext_vector_type(8))) short short8;   // 8 bf16 = 4 VGPRs
typedef __attribute__((ext_vector_type(4))) float floatx4;  // MFMA acc

#define FENCE() __asm__ __volatile__("" ::: "memory")
#define BAR()   do { FENCE(); __builtin_amdgcn_s_barrier(); FENCE(); } while (0)
#define PH_VM(N) __asm__ __volatile__("s_waitcnt vmcnt(" #N ")" ::: "memory")

__device__ __forceinline__ unsigned short f32_to_bf16_rne(float f) {
    union { float f; uint32_t u; } v; v.f = f;
    uint32_t u = v.u;
    return (unsigned short)((u + 0x7FFFu + ((u >> 16) & 1u)) >> 16);
}

// ---- pass 1: x fp32 -> bf16 (8 elems/thread) ----
__global__ __launch_bounds__(256) void convert_x_kernel(
        const float* __restrict__ x, unsigned short* __restrict__ xb) {
    int t = blockIdx.x * 256 + threadIdx.x;
    const float4* p = (const float4*)(x + (size_t)t * 8);
    float4 a = p[0];
    float4 b = p[1];
    short8 o;
    o[0] = (short)f32_to_bf16_rne(a.x);
    o[1] = (short)f32_to_bf16_rne(a.y);
    o[2] = (short)f32_to_bf16_rne(a.z);
    o[3] = (short)f32_to_bf16_rne(a.w);
    o[4] = (short)f32_to_bf16_rne(b.x);
    o[5] = (short)f32_to_bf16_rne(b.y);
    o[6] = (short)f32_to_bf16_rne(b.z);
    o[7] = (short)f32_to_bf16_rne(b.w);
    *(short8*)(xb + (size_t)t * 8) = o;
}

// ---- pass 2: W = ternary * scale -> bf16 (8 elems/thread, all same group) ----
__global__ __launch_bounds__(256) void dequant_w_kernel(
        const int* __restrict__ tern, const float* __restrict__ scales,
        unsigned short* __restrict__ wb) {
    int g = blockIdx.x * 256 + threadIdx.x;          // 8 elems per thread
    float s = scales[g >> 4];                        // (g*8)/128
    const int4* p = (const int4*)(tern + (size_t)g * 8);
    int4 a = p[0];
    int4 b = p[1];
    short8 o;
    o[0] = (short)f32_to_bf16_rne((float)a.x * s);
    o[1] = (short)f32_to_bf16_rne((float)a.y * s);
    o[2] = (short)f32_to_bf16_rne((float)a.z * s);
    o[3] = (short)f32_to_bf16_rne((float)a.w * s);
    o[4] = (short)f32_to_bf16_rne((float)b.x * s);
    o[5] = (short)f32_to_bf16_rne((float)b.y * s);
    o[6] = (short)f32_to_bf16_rne((float)b.z * s);
    o[7] = (short)f32_to_bf16_rne((float)b.w * s);
    *(short8*)(wb + (size_t)g * 8) = o;
}

// ---- pass 3: C = A * B^T, 256x256 tile, BK=32, depth-3 counted-vmcnt pipeline ----
//
// 8 waves (2M x 4N), wave output 128x64. 4 LDS buffers (4 x (A 16KB + B 16KB)
// = 128 KB); tile t+3 staged while computing tile t -> >=8 loads always in
// flight; ONE vmcnt(8) per tile (before the end-of-tile barrier) retires
// exactly tile t+1. Per tile, 2 phases of {ds_read frags BEFORE barrier;
// stage 2 x gload_lds; s_barrier; setprio(1); 16 MFMA; setprio(0); s_barrier}.
// Reads-before-barrier hides LDS latency under barrier arrival; counted vmcnt
// never drains the queue (T3+T4); setprio pays on the phase split (T5).
//
// LDS tile layout (verified 0 bank conflicts in R1): 128-B line L holds rows
// {2L,2L+1}; 16B slot in line = ((r&1)*4 + kchunk) ^ (L&7). gload_lds dest is
// lane-linear; the swizzle is pre-applied to the global source address.
// Cross-wave residency: vmcnt(8) is per-wave, but the following s_barrier
// publishes "my share of tile t+1 landed" from every wave before any reads.
__device__ __forceinline__ floatx4 mfma16(short8 a, short8 b, floatx4 c) {
    return __builtin_amdgcn_mfma_f32_16x16x32_bf16(a, b, c, 0, 0, 0);
}

__device__ __forceinline__ void stage_half(
        const unsigned short* G, unsigned short* Ld,
        int row0, int kofs, const int* srow, const int* scol, const int* sub) {
#pragma unroll
    for (int i = 0; i < 2; ++i) {
        const unsigned short* gsrc =
            G + (size_t)(row0 + srow[i]) * IN_F + kofs + scol[i];
        __builtin_amdgcn_global_load_lds(
            (const __attribute__((address_space(1))) void*)gsrc,
            (__attribute__((address_space(3))) void*)(Ld + sub[i]), 16, 0, 0);
    }
}

// One K-tile: phase 0 computes mfrags 0-3 x nf 0-3, phase 1 mfrags 4-7.
// VMCODE runs once, just before the final barrier.
#define TILE(T, DOSTAGE, VMCODE) do {                                         \
    const unsigned short* _as = &As[(T) & 3][0];                              \
    const unsigned short* _bs = &Bs[(T) & 3][0];                              \
    /* ---- phase 0: reads (8 b128) ; stage A(T+3) ; BAR ; 16 MFMA ; BAR */   \
    _Pragma("unroll")                                                         \
    for (int _m = 0; _m < 4; ++_m) af[_m] = *(const short8*)(_as + a_off[_m]);\
    _Pragma("unroll")                                                         \
    for (int _n = 0; _n < 4; ++_n) bf[_n] = *(const short8*)(_bs + b_off[_n]);\
    if (DOSTAGE)                                                              \
        stage_half(A, &As[((T) + 3) & 3][0], bm, ((T) + 3) * BK,              \
                   srow, scol, sub);                                          \
    BAR();                                                                    \
    __builtin_amdgcn_s_setprio(1);                                            \
    _Pragma("unroll")                                                         \
    for (int _m = 0; _m < 4; ++_m)                                            \
        _Pragma("unroll")                                                     \
        for (int _n = 0; _n < 4; ++_n)                                        \
            acc[_m][_n] = mfma16(af[_m], bf[_n], acc[_m][_n]);                \
    __builtin_amdgcn_s_setprio(0);                                            \
    BAR();                                                                    \
    /* ---- phase 1: reads (4 b128, bf reused) ; stage B(T+3) ; BAR ; MFMA */ \
    _Pragma("unroll")                                                         \
    for (int _m = 0; _m < 4; ++_m)                                            \
        af[_m] = *(const short8*)(_as + a_off[4 + _m]);                       \
    if (DOSTAGE)                                                              \
        stage_half(B, &Bs[((T) + 3) & 3][0], bn, ((T) + 3) * BK,              \
                   srow, scol, sub);                                          \
    BAR();                                                                    \
    __builtin_amdgcn_s_setprio(1);                                            \
    _Pragma("unroll")                                                         \
    for (int _m = 0; _m < 4; ++_m)                                            \
        _Pragma("unroll")                                                     \
        for (int _n = 0; _n < 4; ++_n)                                        \
            acc[4 + _m][_n] = mfma16(af[_m], bf[_n], acc[4 + _m][_n]);        \
    __builtin_amdgcn_s_setprio(0);                                            \
    VMCODE;                                                                   \
    BAR();                                                                    \
} while (0)

__global__ __launch_bounds__(512, 2) void gemm_bt_kernel(
        const unsigned short* __restrict__ A,   // [M_ROWS][IN_F] bf16 bits
        const unsigned short* __restrict__ B,   // [OUT_F][IN_F] bf16 bits
        float* __restrict__ C) {                // [M_ROWS][OUT_F] fp32
    __shared__ unsigned short As[4][8192];      // 4 buf x (256r x 32k) = 64 KB
    __shared__ unsigned short Bs[4][8192];      // 64 KB

    const int tid  = threadIdx.x;
    const int lane = tid & 63;
    const int quad = lane >> 4;        // k-chunk (0..3)
    const int frow = lane & 15;
    const int w    = tid >> 6;         // wave 0..7
    const int wr   = w >> 2;           // 0..1 -> 128 rows each
    const int wc   = w & 3;            // 0..3 -> 64 cols each

    // XCD-bijective swizzle (512 blocks % 8 XCDs == 0): each XCD owns an
    // 8(m) x 8(n) supertile -> B panels shared in its L2 (FETCH 197 MB, R1).
    const int bid = blockIdx.x;
    const int swz = (bid & 7) * 64 + (bid >> 3);
    const int bm  = (swz & 7) * BM;    // 8 m-tiles
    const int bn  = (swz >> 3) * BN;   // 64 n-tiles

    // fragment LDS element-offsets within a tile buffer
    int a_off[8], b_off[4];
#pragma unroll
    for (int mf = 0; mf < 8; ++mf) {
        int r = wr * 128 + mf * 16 + frow;
        a_off[mf] = (r >> 1) * 64 +
                    (((((r & 1) << 2) + quad) ^ ((r >> 1) & 7)) << 3);
    }
#pragma unroll
    for (int nf = 0; nf < 4; ++nf) {
        int r = wc * 64 + nf * 16 + frow;
        b_off[nf] = (r >> 1) * 64 +
                    (((((r & 1) << 2) + quad) ^ ((r >> 1) & 7)) << 3);
    }

    // staging addresses: chunk cid = i*512+tid -> line=cid>>3, k8=(cid&7)^(line&7)
    // -> global row = 2*line + (k8>>2), k-chunk = k8&3. LDS dest linear in cid.
    int srow[2], scol[2], sub[2];
#pragma unroll
    for (int i = 0; i < 2; ++i) {
        int cid = i * 512 + tid;
        int ln  = cid >> 3;
        int k8  = (cid & 7) ^ (ln & 7);
        srow[i] = 2 * ln + (k8 >> 2);
        scol[i] = (k8 & 3) * 8;
        sub[i]  = (i * 512 + (tid & 448)) * 8;   // wave-uniform LDS base (elems)
    }

    floatx4 acc[8][4] = {};
    short8 af[4], bf[4];

    // prologue: stage tiles 0,1,2 (12 loads/thread); retire tile 0, keep 8.
    stage_half(A, &As[0][0], bm, 0 * BK, srow, scol, sub);
    stage_half(B, &Bs[0][0], bn, 0 * BK, srow, scol, sub);
    stage_half(A, &As[1][0], bm, 1 * BK, srow, scol, sub);
    stage_half(B, &Bs[1][0], bn, 1 * BK, srow, scol, sub);
    stage_half(A, &As[2][0], bm, 2 * BK, srow, scol, sub);
    stage_half(B, &Bs[2][0], bn, 2 * BK, srow, scol, sub);
    PH_VM(8);
    BAR();

#pragma unroll 1
    for (int t = 0; t < NT - 3; ++t) {
        TILE(t, true, PH_VM(8));       // stages tile t+3; retires tile t+1
    }
    // epilogue: no more stages; drain 8 -> 4 -> 0
    TILE(NT - 3, false, PH_VM(4));
    TILE(NT - 2, false, PH_VM(0));
    TILE(NT - 1, false, (void)0);

    // epilogue: C/D layout col = lane&15, row = quad*4 + reg  [m89/m91]
    const int row0 = bm + wr * 128 + quad * 4;
    const int col0 = bn + wc * 64 + frow;
#pragma unroll
    for (int mf = 0; mf < 8; ++mf) {
#pragma unroll
        for (int nf = 0; nf < 4; ++nf) {
            float* cp = C + (size_t)(row0 + mf * 16) * OUT_F + (col0 + nf * 16);
#pragma unroll
            for (int r = 0; r < 4; ++r)
                cp[(size_t)r * OUT_F] = acc[mf][nf][r];
        }
    }
}

extern "C" void kernel_launch(void* const* d_in, const int* in_sizes, int n_in,
                              void* d_out, int out_size, void* d_ws, size_t ws_size,
                              hipStream_t stream) {
    const float* x     = (const float*)d_in[0];
    const int*   tern  = (const int*)d_in[1];
    const float* scal  = (const float*)d_in[2];
    float*       out   = (float*)d_out;

    // workspace: x_bf16 (16 MB) then w_bf16 (128 MB)
    unsigned short* xb = (unsigned short*)d_ws;
    unsigned short* wb = xb + (size_t)M_ROWS * IN_F;

    convert_x_kernel<<<(M_ROWS * IN_F / 8) / 256, 256, 0, stream>>>(x, xb);
    dequant_w_kernel<<<((size_t)OUT_F * IN_F / 8) / 256, 256, 0, stream>>>(tern, scal, wb);
    gemm_bt_kernel<<<dim3((M_ROWS / BM) * (OUT_F / BN)), 512, 0, stream>>>(xb, wb, out);
}

// Round 4
// 711.055 us; speedup vs baseline: 1.0584x; 1.0584x over previous
//
#include <hip/hip_runtime.h>
#include <stdint.h>

// Problem constants (QSGDLinear): out = x @ W^T
//   x: (2,1024,4096) fp32 -> M=2048, K=4096
//   ternary: (16384,4096) int32 in {-1,0,1} -> N=16384
//   scales: (16384*4096/128,) fp32, group = contiguous 128 along K of one row
#define M_ROWS 2048
#define IN_F   4096
#define OUT_F  16384

#define BM 128
#define BN 128
#define BK 64

typedef __attribute__((ext_vector_type(8))) short short8;   // 8 bf16 = 4 VGPRs
typedef __attribute__((ext_vector_type(4))) float floatx4;  // MFMA acc

__device__ __forceinline__ unsigned short f32_to_bf16_rne(float f) {
    union { float f; uint32_t u; } v; v.f = f;
    uint32_t u = v.u;
    return (unsigned short)((u + 0x7FFFu + ((u >> 16) & 1u)) >> 16);
}

// ---- fused prepass: x fp32->bf16, W = ternary*scale -> bf16 ----
// Grid-strided, 2048 blocks x 256 thr (8 blocks/CU). Item = 16 elems
// (64 B read). Stride = 2048*256 = 524288 == x item count exactly, so
// iteration 0 handles all of x and iterations 1..8 handle W: branch-free.
__global__ __launch_bounds__(256) void prep_kernel(
        const float* __restrict__ x, const int* __restrict__ tern,
        const float* __restrict__ scales,
        unsigned short* __restrict__ xb, unsigned short* __restrict__ wb) {
    const int NW = (OUT_F / 16) * IN_F;            // 4194304 W items
    const int t  = blockIdx.x * 256 + threadIdx.x; // [0, 524288)

    // ---- x: one item (16 fp32 -> 16 bf16)
    {
        const float4* p = (const float4*)(x + (size_t)t * 16);
        float4 a = p[0], b = p[1], c = p[2], d = p[3];
        short8 o0, o1;
        o0[0] = (short)f32_to_bf16_rne(a.x); o0[1] = (short)f32_to_bf16_rne(a.y);
        o0[2] = (short)f32_to_bf16_rne(a.z); o0[3] = (short)f32_to_bf16_rne(a.w);
        o0[4] = (short)f32_to_bf16_rne(b.x); o0[5] = (short)f32_to_bf16_rne(b.y);
        o0[6] = (short)f32_to_bf16_rne(b.z); o0[7] = (short)f32_to_bf16_rne(b.w);
        o1[0] = (short)f32_to_bf16_rne(c.x); o1[1] = (short)f32_to_bf16_rne(c.y);
        o1[2] = (short)f32_to_bf16_rne(c.z); o1[3] = (short)f32_to_bf16_rne(c.w);
        o1[4] = (short)f32_to_bf16_rne(d.x); o1[5] = (short)f32_to_bf16_rne(d.y);
        o1[6] = (short)f32_to_bf16_rne(d.z); o1[7] = (short)f32_to_bf16_rne(d.w);
        *(short8*)(xb + (size_t)t * 16)     = o0;
        *(short8*)(xb + (size_t)t * 16 + 8) = o1;
    }

    // ---- W: 8 items; 16 elems share one scale (16 | 128)
    for (int wi = t; wi < NW; wi += 524288) {
        float s = scales[wi >> 3];                 // (wi*16)/128
        const int4* p = (const int4*)(tern + (size_t)wi * 16);
        int4 a = p[0], b = p[1], c = p[2], d = p[3];
        short8 o0, o1;
        o0[0] = (short)f32_to_bf16_rne((float)a.x * s);
        o0[1] = (short)f32_to_bf16_rne((float)a.y * s);
        o0[2] = (short)f32_to_bf16_rne((float)a.z * s);
        o0[3] = (short)f32_to_bf16_rne((float)a.w * s);
        o0[4] = (short)f32_to_bf16_rne((float)b.x * s);
        o0[5] = (short)f32_to_bf16_rne((float)b.y * s);
        o0[6] = (short)f32_to_bf16_rne((float)b.z * s);
        o0[7] = (short)f32_to_bf16_rne((float)b.w * s);
        o1[0] = (short)f32_to_bf16_rne((float)c.x * s);
        o1[1] = (short)f32_to_bf16_rne((float)c.y * s);
        o1[2] = (short)f32_to_bf16_rne((float)c.z * s);
        o1[3] = (short)f32_to_bf16_rne((float)c.w * s);
        o1[4] = (short)f32_to_bf16_rne((float)d.x * s);
        o1[5] = (short)f32_to_bf16_rne((float)d.y * s);
        o1[6] = (short)f32_to_bf16_rne((float)d.z * s);
        o1[7] = (short)f32_to_bf16_rne((float)d.w * s);
        *(short8*)(wb + (size_t)wi * 16)     = o0;
        *(short8*)(wb + (size_t)wi * 16 + 8) = o1;
    }
}

// ---- GEMM: C[M,N] = A[M,K] * B[N,K]^T, bf16 in / fp32 out (m97 structure) ----
// PROVEN R0 kernel (281 us, MfmaUtil 44%, 0 bank conflicts) + T1 XCD swizzle.
// Block = 256 threads = 4 waves in 2x2; each wave computes 64x64 via 4x4
// 16x16x32 bf16 MFMAs. LDS tiles staged with global_load_lds width=16.
// XOR swizzle: LDS slot (row, j) holds global k-chunk (j ^ (row&7)) so the
// fragment ds_read_b128 spreads over all 32 banks (2-way aliasing = free).
__global__ __launch_bounds__(256, 3) void gemm_bt_kernel(
        const unsigned short* __restrict__ A,   // [M_ROWS][IN_F] bf16 bits
        const unsigned short* __restrict__ B,   // [OUT_F][IN_F] bf16 bits
        float* __restrict__ C) {                // [M_ROWS][OUT_F] fp32
    __shared__ unsigned short As[BM * BK];      // 16 KB
    __shared__ unsigned short Bs[BN * BK];      // 16 KB

    const int tid  = threadIdx.x;
    const int lane = tid & 63;
    const int quad = lane >> 4;        // 0..3
    const int frow = lane & 15;        // fragment row within 16-tile
    const int r7   = frow & 7;
    const int w    = tid >> 6;         // wave 0..3
    const int wm   = (w & 1) * 64;
    const int wn   = (w >> 1) * 64;

    // T1: XCD-bijective swizzle. Linear id (m-fastest, grid 16x128 = 2048,
    // 2048 % 8 == 0). xcd = lin & 7 owns a contiguous 256-tile chunk
    // (16m x 16n supertile) -> per-XCD L2 working set ~6 MB instead of ~48.
    const int lin = blockIdx.y * 16 + blockIdx.x;
    const int swz = (lin & 7) * 256 + (lin >> 3);
    const int bm  = (swz & 15) * BM;
    const int bn  = (swz >> 4) * BN;

    floatx4 acc[4][4] = {};

    // Precompute LDS fragment element-offsets (constant over kt).
    int a_off[2][4], b_off[2][4];
#pragma unroll
    for (int ks = 0; ks < 2; ++ks) {
        const int j = ks * 4 + quad;            // global k-chunk 0..7
        const int sw = (j ^ r7) * 8;            // swizzled chunk offset in elems
#pragma unroll
        for (int t2 = 0; t2 < 4; ++t2) {
            a_off[ks][t2] = (wm + t2 * 16 + frow) * BK + sw;
            b_off[ks][t2] = (wn + t2 * 16 + frow) * BK + sw;
        }
    }

    for (int kt = 0; kt < IN_F; kt += BK) {
        __syncthreads();
        // stage 32 KB: 2048 chunks of 16 B; 8 global_load_lds per thread
#pragma unroll
        for (int i = 0; i < 4; ++i) {
            const int c    = 256 * i + tid;       // chunk id (per lane)
            const int crow = c >> 3;              // tile row 0..127
            const int jg   = (c & 7) ^ (crow & 7);// swizzled global k-chunk
            const int ub   = (256 * i + (tid & 192)) * 8; // wave-uniform LDS base (elems)
            const unsigned short* ga =
                A + (size_t)(bm + crow) * IN_F + kt + jg * 8;
            const unsigned short* gb =
                B + (size_t)(bn + crow) * IN_F + kt + jg * 8;
            __builtin_amdgcn_global_load_lds(
                (const __attribute__((address_space(1))) void*)ga,
                (__attribute__((address_space(3))) void*)(As + ub), 16, 0, 0);
            __builtin_amdgcn_global_load_lds(
                (const __attribute__((address_space(1))) void*)gb,
                (__attribute__((address_space(3))) void*)(Bs + ub), 16, 0, 0);
        }
        __syncthreads();
        // compute: 2 k-steps of 16 MFMAs
#pragma unroll
        for (int ks = 0; ks < 2; ++ks) {
            short8 af[4], bf[4];
#pragma unroll
            for (int t2 = 0; t2 < 4; ++t2) {
                af[t2] = *(const short8*)(As + a_off[ks][t2]);
                bf[t2] = *(const short8*)(Bs + b_off[ks][t2]);
            }
#pragma unroll
            for (int mt = 0; mt < 4; ++mt)
#pragma unroll
                for (int nt = 0; nt < 4; ++nt)
                    acc[mt][nt] = __builtin_amdgcn_mfma_f32_16x16x32_bf16(
                        af[mt], bf[nt], acc[mt][nt], 0, 0, 0);
        }
    }

    // epilogue: C/D layout col = lane&15, row = quad*4 + reg  [m89/m91]
    const int row0 = bm + wm + quad * 4;
    const int col0 = bn + wn + frow;
#pragma unroll
    for (int mt = 0; mt < 4; ++mt) {
#pragma unroll
        for (int nt = 0; nt < 4; ++nt) {
            float* cp = C + (size_t)(row0 + mt * 16) * OUT_F + (col0 + nt * 16);
#pragma unroll
            for (int r = 0; r < 4; ++r)
                cp[(size_t)r * OUT_F] = acc[mt][nt][r];
        }
    }
}

extern "C" void kernel_launch(void* const* d_in, const int* in_sizes, int n_in,
                              void* d_out, int out_size, void* d_ws, size_t ws_size,
                              hipStream_t stream) {
    const float* x     = (const float*)d_in[0];
    const int*   tern  = (const int*)d_in[1];
    const float* scal  = (const float*)d_in[2];
    float*       out   = (float*)d_out;

    // workspace: x_bf16 (16 MB) then w_bf16 (128 MB)
    unsigned short* xb = (unsigned short*)d_ws;
    unsigned short* wb = xb + (size_t)M_ROWS * IN_F;

    prep_kernel<<<2048, 256, 0, stream>>>(x, tern, scal, xb, wb);
    gemm_bt_kernel<<<dim3(M_ROWS / BM, OUT_F / BN), 256, 0, stream>>>(xb, wb, out);
}

// Round 6
// 679.930 us; speedup vs baseline: 1.1068x; 1.0458x over previous
//
#include <hip/hip_runtime.h>
#include <stdint.h>

// Problem constants (QSGDLinear): out = x @ W^T
//   x: (2,1024,4096) fp32 -> M=2048, K=4096
//   ternary: (16384,4096) int32 in {-1,0,1} -> N=16384
//   scales: (16384*4096/128,) fp32, group = contiguous 128 along K of one row
#define M_ROWS 2048
#define IN_F   4096
#define OUT_F  16384

#define BM 128
#define BN 128
#define BK 64

typedef __attribute__((ext_vector_type(8))) short short8;   // 8 bf16 = 4 VGPRs
typedef __attribute__((ext_vector_type(4))) short short4v;  // 4 bf16 = 8 B
typedef __attribute__((ext_vector_type(4))) float floatx4;  // MFMA acc

__device__ __forceinline__ unsigned short f32_to_bf16_rne(float f) {
    union { float f; uint32_t u; } v; v.f = f;
    uint32_t u = v.u;
    return (unsigned short)((u + 0x7FFFu + ((u >> 16) & 1u)) >> 16);
}

// ---- fused prepass: x fp32->bf16, W = ternary*scale -> bf16 ----
// Grid-strided, 2048 blocks x 256 thr. Per lane per iteration: 16 B read /
// 8 B write, lane-contiguous (proper coalescing; R0/R4 preps were 32-64 B
// lane-strided). x: 4 iterations; W: 32 iterations (scale uniform per 32
// consecutive chunks -> L1-broadcast).
__global__ __launch_bounds__(256) void prep_kernel(
        const float* __restrict__ x, const int* __restrict__ tern,
        const float* __restrict__ scales,
        unsigned short* __restrict__ xb, unsigned short* __restrict__ wb) {
    const int NX4 = M_ROWS * IN_F / 4;             // 2,097,152 float4 chunks
    const int NW4 = OUT_F * (IN_F / 4);            // 16,777,216 int4 chunks
    const int t   = blockIdx.x * 256 + threadIdx.x;

    for (int i = t; i < NX4; i += 524288) {
        float4 a = ((const float4*)x)[i];
        short4v o;
        o[0] = (short)f32_to_bf16_rne(a.x);
        o[1] = (short)f32_to_bf16_rne(a.y);
        o[2] = (short)f32_to_bf16_rne(a.z);
        o[3] = (short)f32_to_bf16_rne(a.w);
        ((short4v*)xb)[i] = o;
    }

    for (int i = t; i < NW4; i += 524288) {
        float s = scales[i >> 5];                  // 32 chunks (128 elems)/group
        int4 v = ((const int4*)tern)[i];
        short4v o;
        o[0] = (short)f32_to_bf16_rne((float)v.x * s);
        o[1] = (short)f32_to_bf16_rne((float)v.y * s);
        o[2] = (short)f32_to_bf16_rne((float)v.z * s);
        o[3] = (short)f32_to_bf16_rne((float)v.w * s);
        ((short4v*)wb)[i] = o;
    }
}

// ---- GEMM: C[M,N] = A[M,K] * B[N,K]^T, bf16 in / fp32 out (m97 structure) ----
// EXACT R0 kernel (281 us, MfmaUtil 44%, 0 bank conflicts) with one change:
// __launch_bounds__(256,4) -> 4 blocks/CU (was 3). LDS 4x32=128<=160 KB;
// unified regs 60 VGPR + 64 AGPR = 124 <= 128/thread at 4 waves/SIMD.
// More co-resident blocks hide the per-block barrier drain (m114 mechanism).
// R4 A/B proved the XCD swizzle HURTS this shape (281->313, FETCH 658->741 MB)
// -- default m-fastest dispatch order is kept.
__global__ __launch_bounds__(256, 4) void gemm_bt_kernel(
        const unsigned short* __restrict__ A,   // [M_ROWS][IN_F] bf16 bits
        const unsigned short* __restrict__ B,   // [OUT_F][IN_F] bf16 bits
        float* __restrict__ C) {                // [M_ROWS][OUT_F] fp32
    __shared__ unsigned short As[BM * BK];      // 16 KB
    __shared__ unsigned short Bs[BN * BK];      // 16 KB

    const int tid  = threadIdx.x;
    const int lane = tid & 63;
    const int quad = lane >> 4;        // 0..3
    const int frow = lane & 15;        // fragment row within 16-tile
    const int r7   = frow & 7;
    const int w    = tid >> 6;         // wave 0..3
    const int wm   = (w & 1) * 64;
    const int wn   = (w >> 1) * 64;

    const int bm = blockIdx.x * BM;    // m fastest -> 16 consecutive blocks share a B tile
    const int bn = blockIdx.y * BN;

    floatx4 acc[4][4] = {};

    // Precompute LDS fragment element-offsets (constant over kt).
    int a_off[2][4], b_off[2][4];
#pragma unroll
    for (int ks = 0; ks < 2; ++ks) {
        const int j = ks * 4 + quad;            // global k-chunk 0..7
        const int sw = (j ^ r7) * 8;            // swizzled chunk offset in elems
#pragma unroll
        for (int t2 = 0; t2 < 4; ++t2) {
            a_off[ks][t2] = (wm + t2 * 16 + frow) * BK + sw;
            b_off[ks][t2] = (wn + t2 * 16 + frow) * BK + sw;
        }
    }

    for (int kt = 0; kt < IN_F; kt += BK) {
        __syncthreads();
        // stage 32 KB: 2048 chunks of 16 B; 8 global_load_lds per thread
#pragma unroll
        for (int i = 0; i < 4; ++i) {
            const int c    = 256 * i + tid;       // chunk id (per lane)
            const int crow = c >> 3;              // tile row 0..127
            const int jg   = (c & 7) ^ (crow & 7);// swizzled global k-chunk
            const int ub   = (256 * i + (tid & 192)) * 8; // wave-uniform LDS base (elems)
            const unsigned short* ga =
                A + (size_t)(bm + crow) * IN_F + kt + jg * 8;
            const unsigned short* gb =
                B + (size_t)(bn + crow) * IN_F + kt + jg * 8;
            __builtin_amdgcn_global_load_lds(
                (const __attribute__((address_space(1))) void*)ga,
                (__attribute__((address_space(3))) void*)(As + ub), 16, 0, 0);
            __builtin_amdgcn_global_load_lds(
                (const __attribute__((address_space(1))) void*)gb,
                (__attribute__((address_space(3))) void*)(Bs + ub), 16, 0, 0);
        }
        __syncthreads();
        // compute: 2 k-steps of 16 MFMAs
#pragma unroll
        for (int ks = 0; ks < 2; ++ks) {
            short8 af[4], bf[4];
#pragma unroll
            for (int t2 = 0; t2 < 4; ++t2) {
                af[t2] = *(const short8*)(As + a_off[ks][t2]);
                bf[t2] = *(const short8*)(Bs + b_off[ks][t2]);
            }
#pragma unroll
            for (int mt = 0; mt < 4; ++mt)
#pragma unroll
                for (int nt = 0; nt < 4; ++nt)
                    acc[mt][nt] = __builtin_amdgcn_mfma_f32_16x16x32_bf16(
                        af[mt], bf[nt], acc[mt][nt], 0, 0, 0);
        }
    }

    // epilogue: C/D layout col = lane&15, row = quad*4 + reg  [m89/m91]
    const int row0 = bm + wm + quad * 4;
    const int col0 = bn + wn + frow;
#pragma unroll
    for (int mt = 0; mt < 4; ++mt) {
#pragma unroll
        for (int nt = 0; nt < 4; ++nt) {
            float* cp = C + (size_t)(row0 + mt * 16) * OUT_F + (col0 + nt * 16);
#pragma unroll
            for (int r = 0; r < 4; ++r)
                cp[(size_t)r * OUT_F] = acc[mt][nt][r];
        }
    }
}

extern "C" void kernel_launch(void* const* d_in, const int* in_sizes, int n_in,
                              void* d_out, int out_size, void* d_ws, size_t ws_size,
                              hipStream_t stream) {
    const float* x     = (const float*)d_in[0];
    const int*   tern  = (const int*)d_in[1];
    const float* scal  = (const float*)d_in[2];
    float*       out   = (float*)d_out;

    // workspace: x_bf16 (16 MB) then w_bf16 (128 MB)
    unsigned short* xb = (unsigned short*)d_ws;
    unsigned short* wb = xb + (size_t)M_ROWS * IN_F;

    prep_kernel<<<2048, 256, 0, stream>>>(x, tern, scal, xb, wb);
    gemm_bt_kernel<<<dim3(M_ROWS / BM, OUT_F / BN), 256, 0, stream>>>(xb, wb, out);
}